// Round 7
// baseline (475.356 us; speedup 1.0000x reference)
//
#include <hip/hip_runtime.h>
#include <hip/hip_bf16.h>

#define S 4096
#define D 2048
#define NH 16
#define HD 128

typedef __attribute__((ext_vector_type(8))) short bf16x8;
typedef __attribute__((ext_vector_type(4))) float f32x4;

typedef __attribute__((address_space(1))) char glob_char;
typedef __attribute__((address_space(3))) char lds_char_t;

__device__ __forceinline__ void gld16(const void* g, void* l) {
    __builtin_amdgcn_global_load_lds((const glob_char*)g, (lds_char_t*)l, 16, 0, 0);
}

__device__ __forceinline__ unsigned short f2b(float f) {
    union { float f; unsigned u; } c; c.f = f;
    unsigned r = c.u + 0x7fff + ((c.u >> 16) & 1);
    return (unsigned short)(r >> 16);
}

__device__ __forceinline__ float fexp2(float x) {
#if __has_builtin(__builtin_amdgcn_exp2f)
    return __builtin_amdgcn_exp2f(x);
#else
    return __expf(x * 0.6931471805599453f);
#endif
}

// pack two f32 -> one u32 of 2 bf16 (lo = a, hi = b), RNE.
// Manual pack via f2b: semantics fully defined, no header/ISA dependence.
__device__ __forceinline__ unsigned pk2(float a, float b) {
    return (unsigned)f2b(a) | ((unsigned)f2b(b) << 16);
}

__device__ __forceinline__ bf16x8 mkfrag(unsigned a, unsigned b, unsigned c, unsigned d) {
    union { unsigned u[4]; bf16x8 v; } x;
    x.u[0] = a; x.u[1] = b; x.u[2] = c; x.u[3] = d;
    return x.v;
}

#define MFMA16(a, b, c) __builtin_amdgcn_mfma_f32_16x16x32_bf16((a), (b), (c), 0, 0, 0)

// ---------------- fp32 -> bf16 conversion (all 5 tensors, one launch) ----
__global__ __launch_bounds__(256) void cvt_all(
    const float* __restrict__ x,  const float* __restrict__ wq,
    const float* __restrict__ wk, const float* __restrict__ wv,
    const float* __restrict__ wo,
    unsigned short* __restrict__ xb, unsigned short* __restrict__ wqkvb,
    unsigned short* __restrict__ wob)
{
    const int z = blockIdx.y;
    const float* src; unsigned short* dst; int n4;
    if (z == 0)      { src = x;  dst = xb;                        n4 = (S * D) / 4; }
    else if (z == 1) { src = wq; dst = wqkvb;                     n4 = (D * D) / 4; }
    else if (z == 2) { src = wk; dst = wqkvb + (size_t)D * D;     n4 = (D * D) / 4; }
    else if (z == 3) { src = wv; dst = wqkvb + 2 * (size_t)D * D; n4 = (D * D) / 4; }
    else             { src = wo; dst = wob;                       n4 = (D * D) / 4; }
    int i = blockIdx.x * 256 + threadIdx.x;
    if (i < n4) {
        float4 v = ((const float4*)src)[i];
        ushort4 o;
        o.x = f2b(v.x); o.y = f2b(v.y); o.z = f2b(v.z); o.w = f2b(v.w);
        ((ushort4*)dst)[i] = o;
    }
}

// ---------------- bf16 NT GEMM, 256x256 tile, 8-phase/2-K-tile -----------
// (unchanged — see round 3 ledger in comments)
template<int OUTMODE>
__global__ __launch_bounds__(512, 2) void gemm8(
    const unsigned short* __restrict__ A, const unsigned short* __restrict__ B,
    void* __restrict__ O0, void* __restrict__ O1, void* __restrict__ O2,
    const float* __restrict__ qw, const float* __restrict__ kw)
{
    __shared__ short lds[65536];      // A: [2buf][256][64] at 0; B at 32768
    __shared__ float red[4][256];

    const int tid = threadIdx.x;
    const int lane = tid & 63, col = lane & 15, quad = lane >> 4;
    const int w = tid >> 6, wr = w >> 2, wc = w & 3;

    // T1: bijective XCD swizzle (nwg % 8 == 0 for both launches)
    const int nwg = gridDim.x * gridDim.y;
    const int orig = blockIdx.y * gridDim.x + blockIdx.x;
    const int lin = (orig & 7) * (nwg >> 3) + (orig >> 3);
    const int m0 = (lin / gridDim.x) * 256;
    const int n0 = (lin % gridDim.x) * 256;

    const int srow = tid >> 3;                        // 0..63
    const int sslot = (tid & 7) ^ (srow & 7);         // inverse swizzle
    const unsigned short* pa0 = A + (size_t)(m0 + srow) * 2048 + sslot * 8;
    const unsigned short* pb0 = B + (size_t)(n0 + srow) * 2048 + sslot * 8;
    const int dst0 = tid * 8;                         // shorts; it=1: +4096

    auto stA = [&](int t, int h, int buf) {
        const unsigned short* g = pa0 + (size_t)h * 262144 + t * 64;
        short* d = &lds[buf * 16384 + h * 8192 + dst0];
        gld16(g, d);
        gld16(g + 131072, d + 4096);                  // rows +64
    };
    auto stB = [&](int t, int h, int buf) {
        const unsigned short* g = pb0 + (size_t)h * 262144 + t * 64;
        short* d = &lds[32768 + buf * 16384 + h * 8192 + dst0];
        gld16(g, d);
        gld16(g + 131072, d + 4096);
    };

    const int sl0 = (quad ^ (col & 7)) << 3;          // shorts; kk=1: ^32
    const int arow = (wr * 128 + col) * 64;
    const int brow = (wc * 64 + col) * 64;
    auto rdA = [&](int mf, int kk, int buf) -> bf16x8 {
        return *(const bf16x8*)&lds[buf * 16384 + arow + mf * 1024 + (sl0 ^ (kk << 5))];
    };
    auto rdB = [&](int nf, int kk, int buf) -> bf16x8 {
        return *(const bf16x8*)&lds[32768 + buf * 16384 + brow + nf * 1024 + (sl0 ^ (kk << 5))];
    };

    f32x4 acc[8][4];
    #pragma unroll
    for (int i = 0; i < 8; ++i)
        #pragma unroll
        for (int j = 0; j < 4; ++j)
            #pragma unroll
            for (int r = 0; r < 4; ++r) acc[i][j][r] = 0.0f;

    auto ktile = [&](int buf, int tst, int mode) {
        bf16x8 a0[4][2], a1[4][2], b0[2][2], b1[2][2];
        #pragma unroll
        for (int mf = 0; mf < 4; ++mf) { a0[mf][0] = rdA(mf, 0, buf); a0[mf][1] = rdA(mf, 1, buf); }
        #pragma unroll
        for (int nf = 0; nf < 2; ++nf) { b0[nf][0] = rdB(nf, 0, buf); b0[nf][1] = rdB(nf, 1, buf); }
        __builtin_amdgcn_s_barrier();
        __builtin_amdgcn_s_setprio(1);
        #pragma unroll
        for (int mf = 0; mf < 4; ++mf)
            #pragma unroll
            for (int nf = 0; nf < 2; ++nf) {
                acc[mf][nf] = MFMA16(a0[mf][0], b0[nf][0], acc[mf][nf]);
                acc[mf][nf] = MFMA16(a0[mf][1], b0[nf][1], acc[mf][nf]);
            }
        __builtin_amdgcn_s_setprio(0);
        __builtin_amdgcn_s_barrier();

        #pragma unroll
        for (int mf = 0; mf < 4; ++mf) { a1[mf][0] = rdA(mf + 4, 0, buf); a1[mf][1] = rdA(mf + 4, 1, buf); }
        __builtin_amdgcn_s_barrier();
        __builtin_amdgcn_s_setprio(1);
        #pragma unroll
        for (int mf = 0; mf < 4; ++mf)
            #pragma unroll
            for (int nf = 0; nf < 2; ++nf) {
                acc[mf + 4][nf] = MFMA16(a1[mf][0], b0[nf][0], acc[mf + 4][nf]);
                acc[mf + 4][nf] = MFMA16(a1[mf][1], b0[nf][1], acc[mf + 4][nf]);
            }
        __builtin_amdgcn_s_setprio(0);
        __builtin_amdgcn_s_barrier();

        #pragma unroll
        for (int nf = 0; nf < 2; ++nf) { b1[nf][0] = rdB(nf + 2, 0, buf); b1[nf][1] = rdB(nf + 2, 1, buf); }
        if (mode == 0) { stA(tst, 0, buf); stA(tst, 1, buf); }
        __builtin_amdgcn_s_barrier();
        __builtin_amdgcn_s_setprio(1);
        #pragma unroll
        for (int mf = 0; mf < 4; ++mf)
            #pragma unroll
            for (int nf = 0; nf < 2; ++nf) {
                acc[mf][nf + 2] = MFMA16(a0[mf][0], b1[nf][0], acc[mf][nf + 2]);
                acc[mf][nf + 2] = MFMA16(a0[mf][1], b1[nf][1], acc[mf][nf + 2]);
            }
        __builtin_amdgcn_s_setprio(0);
        __builtin_amdgcn_s_barrier();

        if (mode == 0) { stB(tst, 0, buf); stB(tst, 1, buf); }
        __builtin_amdgcn_s_barrier();
        __builtin_amdgcn_s_setprio(1);
        #pragma unroll
        for (int mf = 0; mf < 4; ++mf)
            #pragma unroll
            for (int nf = 0; nf < 2; ++nf) {
                acc[mf + 4][nf + 2] = MFMA16(a1[mf][0], b1[nf][0], acc[mf + 4][nf + 2]);
                acc[mf + 4][nf + 2] = MFMA16(a1[mf][1], b1[nf][1], acc[mf + 4][nf + 2]);
            }
        __builtin_amdgcn_s_setprio(0);
        if (mode == 0)      asm volatile("s_waitcnt vmcnt(8)" ::: "memory");
        else if (mode == 1) asm volatile("s_waitcnt vmcnt(0)" ::: "memory");
        __builtin_amdgcn_s_barrier();
    };

    stA(0, 0, 0); stA(0, 1, 0); stB(0, 0, 0); stB(0, 1, 0);
    stA(1, 0, 1); stA(1, 1, 1); stB(1, 0, 1); stB(1, 1, 1);
    asm volatile("s_waitcnt vmcnt(8)" ::: "memory");
    __builtin_amdgcn_s_barrier();

    for (int kt = 0; kt < 16; ++kt) {
        const int t0 = kt << 1;
        const bool st = kt < 15;
        ktile(0, t0 + 2, st ? 0 : 1);
        ktile(1, t0 + 3, st ? 0 : 2);
    }

    // ---------------- epilogue ----------------
    if (OUTMODE == 1) {
        float* C = (float*)O0;
        #pragma unroll
        for (int mf = 0; mf < 8; ++mf)
            #pragma unroll
            for (int nf = 0; nf < 4; ++nf)
                #pragma unroll
                for (int r = 0; r < 4; ++r)
                    C[(size_t)(m0 + wr * 128 + mf * 16 + quad * 4 + r) * 2048 +
                      n0 + wc * 64 + nf * 16 + col] = acc[mf][nf][r];
    } else {
        const int sel = n0 >> 11;
        if (sel == 2) {
            unsigned short* VtO = (unsigned short*)O2;
            #pragma unroll
            for (int mf = 0; mf < 8; ++mf)
                #pragma unroll
                for (int nf = 0; nf < 4; ++nf) {
                    int n = (n0 & 2047) + wc * 64 + nf * 16 + col;
                    int hh = n >> 7, dv = n & 127;
                    ushort4 pk;
                    pk.x = f2b(acc[mf][nf][0]); pk.y = f2b(acc[mf][nf][1]);
                    pk.z = f2b(acc[mf][nf][2]); pk.w = f2b(acc[mf][nf][3]);
                    *(ushort4*)&VtO[(size_t)hh * (HD * S) + (size_t)dv * S +
                                    m0 + wr * 128 + mf * 16 + quad * 4] = pk;
                }
        } else {
            unsigned short* C = (unsigned short*)(sel == 0 ? O0 : O1);
            const float* wgt = (sel == 0) ? qw : kw;
            const float extra = (sel == 0)
                ? 0.08838834764831845f * 1.4426950408889634f : 1.0f;
            float wv4[4];
            #pragma unroll
            for (int nf = 0; nf < 4; ++nf)
                wv4[nf] = wgt[(wc & 1) * 64 + nf * 16 + col];
            #pragma unroll
            for (int mf = 0; mf < 8; ++mf)
                #pragma unroll
                for (int r = 0; r < 4; ++r) {
                    float ss = 0.0f;
                    #pragma unroll
                    for (int nf = 0; nf < 4; ++nf) ss += acc[mf][nf][r] * acc[mf][nf][r];
                    #pragma unroll
                    for (int d = 1; d < 16; d <<= 1) ss += __shfl_xor(ss, d, 64);
                    if (col == 0) red[wc][wr * 128 + mf * 16 + quad * 4 + r] = ss;
                }
            __syncthreads();
            #pragma unroll
            for (int mf = 0; mf < 8; ++mf) {
                float rsc[4];
                #pragma unroll
                for (int r = 0; r < 4; ++r) {
                    int idx = wr * 128 + mf * 16 + quad * 4 + r;
                    float tot = red[wc & 6][idx] + red[(wc & 6) + 1][idx];
                    rsc[r] = rsqrtf(tot * (1.0f / HD) + 1e-6f) * extra;
                }
                #pragma unroll
                for (int nf = 0; nf < 4; ++nf)
                    #pragma unroll
                    for (int r = 0; r < 4; ++r)
                        C[(size_t)(m0 + wr * 128 + mf * 16 + quad * 4 + r) * 2048 +
                          (n0 & 2047) + wc * 64 + nf * 16 + col] =
                            f2b(acc[mf][nf][r] * rsc[r] * wv4[nf]);
            }
        }
    }
}

// ---------------- MFMA flash attention v6.1 ------------------------------
// Swapped QK^T (MFMA(K,Q)) -> P^T in registers: P[key=kj*16+quad*4+r][q=col].
// exp2 in regs; pk2 (manual f2b pack, lo|hi<<16) packs pairs; 32 shfl +
// cndmask redistribute into PV A-frags:
//   apw[qs][ks][j2] <- wp[qs][2ks+(quad>>1)][j2&1] from lane
//   col + 32*(quad&1) + 16*(j2>>1).
// No Ps LDS (80->64KB), no ds_write/lgkm serialization in softmax.
struct FlashSmem {
    short Ks[2][8192];   // [buf][ds][key][chunk]
    short Vs[2][8192];   // [buf][ks][dv][chunk]
};

__global__ __launch_bounds__(256, 2) void flash_mfma(
    const unsigned short* __restrict__ Qg, const unsigned short* __restrict__ Kg,
    const unsigned short* __restrict__ Vt, unsigned short* __restrict__ Ctx)
{
    __shared__ FlashSmem sm;

    const int tid = threadIdx.x;
    const int w = tid >> 6, lane = tid & 63, col = lane & 15, quad = lane >> 4;
    const int q0 = blockIdx.x * 128, h = blockIdx.y;

    // Q fragments (pre-scaled by log2e/sqrt(HD) in the projection epilogue)
    bf16x8 aq[2][4];
    #pragma unroll
    for (int qs = 0; qs < 2; ++qs) {
        const size_t qoff = (size_t)(q0 + w * 32 + qs * 16 + col) * 2048 + h * 128 + quad * 8;
        #pragma unroll
        for (int ds = 0; ds < 4; ++ds)
            aq[qs][ds] = *(const bf16x8*)&Qg[qoff + ds * 32];
    }

    const unsigned short* kga[4];
    const unsigned short* vga[4];
    #pragma unroll
    for (int it = 0; it < 4; ++it) {
        int c = tid + (it << 8);
        {   int ds = c >> 8, rem = c & 255, key = rem >> 2, ch = rem & 3;
            int g = ch ^ ((key >> 1) & 3);
            kga[it] = &Kg[(size_t)key * 2048 + h * 128 + ds * 32 + g * 8]; }
        {   int ks = c >> 9, rem = c & 511, dv = rem >> 2, ch = rem & 3;
            int g = ch ^ ((dv >> 1) & 3);
            vga[it] = &Vt[(size_t)h * (HD * S) + (size_t)dv * S + ks * 32 + g * 8]; }
    }

    const int fb = col * 32 + ((quad ^ ((col >> 1) & 3)) << 3);
    const int src0 = col + 32 * (quad & 1);   // shuffle source, g=0

    bf16x8 vone;
    #pragma unroll
    for (int i = 0; i < 8; ++i) vone[i] = (short)0x3F80;

    f32x4 lacc[2];
    f32x4 o[2][8];
    #pragma unroll
    for (int qs = 0; qs < 2; ++qs) {
        #pragma unroll
        for (int r = 0; r < 4; ++r) lacc[qs][r] = 0.0f;
        #pragma unroll
        for (int nj = 0; nj < 8; ++nj)
            #pragma unroll
            for (int r = 0; r < 4; ++r) o[qs][nj][r] = 0.0f;
    }

    auto stage = [&](int b) {
        #pragma unroll
        for (int it = 0; it < 4; ++it) {
            gld16(kga[it], &sm.Ks[b][(tid + (it << 8)) * 8]);
            kga[it] += 64 * 2048;
        }
        #pragma unroll
        for (int it = 0; it < 4; ++it) {
            gld16(vga[it], &sm.Vs[b][(tid + (it << 8)) * 8]);
            vga[it] += 64;
        }
    };

    auto compute = [&](int b) {
        // ---- QK^T swapped: P[key = kj*16 + quad*4 + r][q = qs*16 + col] --
        f32x4 sc[2][4];
        #pragma unroll
        for (int qs = 0; qs < 2; ++qs)
            #pragma unroll
            for (int kj = 0; kj < 4; ++kj)
                #pragma unroll
                for (int r = 0; r < 4; ++r) sc[qs][kj][r] = 0.0f;
        __builtin_amdgcn_s_setprio(1);
        #pragma unroll
        for (int ds = 0; ds < 4; ++ds)
            #pragma unroll
            for (int kj = 0; kj < 4; ++kj) {
                bf16x8 bk = *(const bf16x8*)&sm.Ks[b][fb + ds * 2048 + kj * 512];
                sc[0][kj] = MFMA16(bk, aq[0][ds], sc[0][kj]);
                sc[1][kj] = MFMA16(bk, aq[1][ds], sc[1][kj]);
            }
        __builtin_amdgcn_s_setprio(0);

        // ---- exp2 in registers ----
        #pragma unroll
        for (int qs = 0; qs < 2; ++qs)
            #pragma unroll
            for (int kj = 0; kj < 4; ++kj)
                #pragma unroll
                for (int r = 0; r < 4; ++r)
                    sc[qs][kj][r] = fexp2(sc[qs][kj][r]);

        // ---- pack pairs: wp[qs][kj][h] = keys kj*16 + quad*4 + {2h,2h+1} --
        unsigned wp[2][4][2];
        #pragma unroll
        for (int qs = 0; qs < 2; ++qs)
            #pragma unroll
            for (int kj = 0; kj < 4; ++kj)
                #pragma unroll
                for (int hh = 0; hh < 2; ++hh)
                    wp[qs][kj][hh] = pk2(sc[qs][kj][2 * hh], sc[qs][kj][2 * hh + 1]);

        // ---- redistribute into PV A-frags via shfl + select ----
        unsigned apw[2][2][4];    // [qs][ks][j2]
        #pragma unroll
        for (int qs = 0; qs < 2; ++qs)
            #pragma unroll
            for (int g = 0; g < 2; ++g) {
                const int srcl = src0 + 16 * g;
                #pragma unroll
                for (int hh = 0; hh < 2; ++hh) {
                    unsigned t0 = (unsigned)__shfl((int)wp[qs][0][hh], srcl, 64);
                    unsigned t1 = (unsigned)__shfl((int)wp[qs][1][hh], srcl, 64);
                    unsigned t2 = (unsigned)__shfl((int)wp[qs][2][hh], srcl, 64);
                    unsigned t3 = (unsigned)__shfl((int)wp[qs][3][hh], srcl, 64);
                    const int j2 = 2 * g + hh;
                    apw[qs][0][j2] = (quad & 2) ? t1 : t0;
                    apw[qs][1][j2] = (quad & 2) ? t3 : t2;
                }
            }
        bf16x8 ap[2][2];
        #pragma unroll
        for (int qs = 0; qs < 2; ++qs)
            #pragma unroll
            for (int ks = 0; ks < 2; ++ks)
                ap[qs][ks] = mkfrag(apw[qs][ks][0], apw[qs][ks][1],
                                    apw[qs][ks][2], apw[qs][ks][3]);

        // ---- O += P @ V ; l += P @ ones ----
        __builtin_amdgcn_s_setprio(1);
        #pragma unroll
        for (int ks = 0; ks < 2; ++ks) {
            lacc[0] = MFMA16(ap[0][ks], vone, lacc[0]);
            lacc[1] = MFMA16(ap[1][ks], vone, lacc[1]);
            #pragma unroll
            for (int nj = 0; nj < 8; ++nj) {
                bf16x8 bv = *(const bf16x8*)&sm.Vs[b][fb + ks * 4096 + nj * 512];
                o[0][nj] = MFMA16(ap[0][ks], bv, o[0][nj]);
                o[1][nj] = MFMA16(ap[1][ks], bv, o[1][nj]);
            }
        }
        __builtin_amdgcn_s_setprio(0);
    };

    stage(0);
    for (int j0 = 0; j0 < S; j0 += 128) {
        __syncthreads();
        stage(1);
        compute(0);
        __syncthreads();
        if (j0 + 128 < S) stage(0);
        compute(1);
    }

    // l is per-lane complete for q = qs*16 + quad*4 + r rows (D-layout)
    #pragma unroll
    for (int qs = 0; qs < 2; ++qs) {
        float inv[4];
        #pragma unroll
        for (int r = 0; r < 4; ++r) inv[r] = 1.0f / lacc[qs][r];
        #pragma unroll
        for (int nj = 0; nj < 8; ++nj)
            #pragma unroll
            for (int r = 0; r < 4; ++r)
                Ctx[(size_t)(q0 + w * 32 + qs * 16 + quad * 4 + r) * 2048 + h * 128 + nj * 16 + col] =
                    f2b(o[qs][nj][r] * inv[r]);
    }
}

extern "C" void kernel_launch(void* const* d_in, const int* in_sizes, int n_in,
                              void* d_out, int out_size, void* d_ws, size_t ws_size,
                              hipStream_t stream)
{
    const float* x  = (const float*)d_in[0];
    const float* wq = (const float*)d_in[1];
    const float* wk = (const float*)d_in[2];
    const float* wv = (const float*)d_in[3];
    const float* wo = (const float*)d_in[4];
    const float* qw = (const float*)d_in[5];
    const float* kw = (const float*)d_in[6];
    float* out = (float*)d_out;

    const size_t MB = 1u << 20;
    char* ws = (char*)d_ws;
    unsigned short* xb    = (unsigned short*)(ws);             // 16 MB; later Ctx
    unsigned short* Wqkvb = (unsigned short*)(ws + 16 * MB);   // 24 MB
    unsigned short* Wob   = (unsigned short*)(ws + 40 * MB);   //  8 MB
    unsigned short* Qb    = (unsigned short*)(ws + 48 * MB);   // 16 MB
    unsigned short* Kb    = (unsigned short*)(ws + 64 * MB);   // 16 MB
    unsigned short* Vt    = (unsigned short*)(ws + 80 * MB);   // 16 MB [h][dv][s]
    unsigned short* Ctx   = xb;                                // overlay after proj

    cvt_all<<<dim3(8192, 5), dim3(256), 0, stream>>>(x, wq, wk, wv, wo, xb, Wqkvb, Wob);

    // fused QKV projection + RMSNorm epilogue + transposed V write
    gemm8<0><<<dim3(24, 16), dim3(512), 0, stream>>>(xb, Wqkvb, Qb, Kb, Vt, qw, kw);

    flash_mfma<<<dim3(32, 16), dim3(256), 0, stream>>>(Qb, Kb, Vt, Ctx);

    gemm8<1><<<dim3(8, 16), dim3(512), 0, stream>>>(Ctx, Wob, out, out, out, qw, kw);
}

// Round 9
// 451.636 us; speedup vs baseline: 1.0525x; 1.0525x over previous
//
#include <hip/hip_runtime.h>
#include <hip/hip_bf16.h>

#define S 4096
#define D 2048
#define NH 16
#define HD 128

typedef __attribute__((ext_vector_type(8))) short bf16x8;
typedef __attribute__((ext_vector_type(4))) float f32x4;

typedef __attribute__((address_space(1))) char glob_char;
typedef __attribute__((address_space(3))) char lds_char_t;

__device__ __forceinline__ void gld16(const void* g, void* l) {
    __builtin_amdgcn_global_load_lds((const glob_char*)g, (lds_char_t*)l, 16, 0, 0);
}

__device__ __forceinline__ unsigned short f2b(float f) {
    union { float f; unsigned u; } c; c.f = f;
    unsigned r = c.u + 0x7fff + ((c.u >> 16) & 1);
    return (unsigned short)(r >> 16);
}
__device__ __forceinline__ float b2f(unsigned short u) {
    union { unsigned u; float f; } c; c.u = ((unsigned)u) << 16;
    return c.f;
}

__device__ __forceinline__ float fexp2(float x) {
#if __has_builtin(__builtin_amdgcn_exp2f)
    return __builtin_amdgcn_exp2f(x);
#else
    return __expf(x * 0.6931471805599453f);
#endif
}

#define MFMA16(a, b, c) __builtin_amdgcn_mfma_f32_16x16x32_bf16((a), (b), (c), 0, 0, 0)

// ---------------- fp32 -> bf16 conversion (all 5 tensors, one launch) ----
__global__ __launch_bounds__(256) void cvt_all(
    const float* __restrict__ x,  const float* __restrict__ wq,
    const float* __restrict__ wk, const float* __restrict__ wv,
    const float* __restrict__ wo,
    unsigned short* __restrict__ xb, unsigned short* __restrict__ wqkvb,
    unsigned short* __restrict__ wob)
{
    const int z = blockIdx.y;
    const float* src; unsigned short* dst; int n4;
    if (z == 0)      { src = x;  dst = xb;                        n4 = (S * D) / 4; }
    else if (z == 1) { src = wq; dst = wqkvb;                     n4 = (D * D) / 4; }
    else if (z == 2) { src = wk; dst = wqkvb + (size_t)D * D;     n4 = (D * D) / 4; }
    else if (z == 3) { src = wv; dst = wqkvb + 2 * (size_t)D * D; n4 = (D * D) / 4; }
    else             { src = wo; dst = wob;                       n4 = (D * D) / 4; }
    int i = blockIdx.x * 256 + threadIdx.x;
    if (i < n4) {
        float4 v = ((const float4*)src)[i];
        ushort4 o;
        o.x = f2b(v.x); o.y = f2b(v.y); o.z = f2b(v.z); o.w = f2b(v.w);
        ((ushort4*)dst)[i] = o;
    }
}

// ---------------- bf16 NT GEMM, 256x256 tile, 8-phase schedule -----------
// Round-3 version (best measured total). QKV projection only (OUTMODE 0
// semantics: n<2048 Q w/ RMSNorm*log2e/sqrt(HD); [2048,4096) K w/ RMSNorm;
// >=4096 V transposed to Vt[h][dv][s]).
__global__ __launch_bounds__(512, 2) void gemm8_qkv(
    const unsigned short* __restrict__ A, const unsigned short* __restrict__ B,
    void* __restrict__ O0, void* __restrict__ O1, void* __restrict__ O2,
    const float* __restrict__ qw, const float* __restrict__ kw)
{
    __shared__ short lds[65536];      // A: [2buf][256][64] at 0; B at 32768
    __shared__ float red[4][256];

    const int tid = threadIdx.x;
    const int lane = tid & 63, col = lane & 15, quad = lane >> 4;
    const int w = tid >> 6, wr = w >> 2, wc = w & 3;
    const int m0 = blockIdx.y * 256, n0 = blockIdx.x * 256;

    const int srow = tid >> 3;                        // 0..63
    const int sslot = (tid & 7) ^ (srow & 7);         // inverse swizzle
    const unsigned short* pa0 = A + (size_t)(m0 + srow) * 2048 + sslot * 8;
    const unsigned short* pb0 = B + (size_t)(n0 + srow) * 2048 + sslot * 8;
    const int dst0 = tid * 8;                         // shorts; it=1: +4096

    auto stA = [&](int t, int h, int buf) {
        const unsigned short* g = pa0 + (size_t)h * 262144 + t * 64;
        short* d = &lds[buf * 16384 + h * 8192 + dst0];
        gld16(g, d);
        gld16(g + 131072, d + 4096);                  // rows +64
    };
    auto stB = [&](int t, int h, int buf) {
        const unsigned short* g = pb0 + (size_t)h * 262144 + t * 64;
        short* d = &lds[32768 + buf * 16384 + h * 8192 + dst0];
        gld16(g, d);
        gld16(g + 131072, d + 4096);
    };

    const int sl0 = (quad ^ (col & 7)) << 3;          // shorts; kk=1: ^32
    const int arow = (wr * 128 + col) * 64;
    const int brow = (wc * 64 + col) * 64;
    auto rdA = [&](int mf, int kk, int buf) -> bf16x8 {
        return *(const bf16x8*)&lds[buf * 16384 + arow + mf * 1024 + (sl0 ^ (kk << 5))];
    };
    auto rdB = [&](int nf, int kk, int buf) -> bf16x8 {
        return *(const bf16x8*)&lds[32768 + buf * 16384 + brow + nf * 1024 + (sl0 ^ (kk << 5))];
    };

    f32x4 acc[8][4];
    #pragma unroll
    for (int i = 0; i < 8; ++i)
        #pragma unroll
        for (int j = 0; j < 4; ++j)
            #pragma unroll
            for (int r = 0; r < 4; ++r) acc[i][j][r] = 0.0f;

    // prologue: tile0 full + tile1 A-halves; wait tile0 landed
    stA(0, 0, 0); stA(0, 1, 0); stB(0, 0, 0); stB(0, 1, 0);
    stA(1, 0, 1); stA(1, 1, 1);
    asm volatile("s_waitcnt vmcnt(4)" ::: "memory");
    __builtin_amdgcn_s_barrier();

    for (int t = 0; t < 32; ++t) {
        const int cur = t & 1, nxt = cur ^ 1;
        const bool s1 = t < 31, s2 = t < 30;
        bf16x8 a0[4][2], a1[4][2], b0[2][2], b1[2][2];

        // ph1: a0 + b0, stage t+1.B.h0, MFMA (M0,N0)
        #pragma unroll
        for (int mf = 0; mf < 4; ++mf) { a0[mf][0] = rdA(mf, 0, cur); a0[mf][1] = rdA(mf, 1, cur); }
        #pragma unroll
        for (int nf = 0; nf < 2; ++nf) { b0[nf][0] = rdB(nf, 0, cur); b0[nf][1] = rdB(nf, 1, cur); }
        if (s1) stB(t + 1, 0, nxt);
        __builtin_amdgcn_s_barrier();
        __builtin_amdgcn_s_setprio(1);
        #pragma unroll
        for (int mf = 0; mf < 4; ++mf)
            #pragma unroll
            for (int nf = 0; nf < 2; ++nf) {
                acc[mf][nf] = MFMA16(a0[mf][0], b0[nf][0], acc[mf][nf]);
                acc[mf][nf] = MFMA16(a0[mf][1], b0[nf][1], acc[mf][nf]);
            }
        __builtin_amdgcn_s_setprio(0);
        __builtin_amdgcn_s_barrier();

        // ph2: a1 + b1, stage t+1.B.h1, MFMA (M0,N1)
        #pragma unroll
        for (int mf = 0; mf < 4; ++mf) { a1[mf][0] = rdA(mf + 4, 0, cur); a1[mf][1] = rdA(mf + 4, 1, cur); }
        #pragma unroll
        for (int nf = 0; nf < 2; ++nf) { b1[nf][0] = rdB(nf + 2, 0, cur); b1[nf][1] = rdB(nf + 2, 1, cur); }
        if (s1) stB(t + 1, 1, nxt);
        __builtin_amdgcn_s_barrier();
        __builtin_amdgcn_s_setprio(1);
        #pragma unroll
        for (int mf = 0; mf < 4; ++mf)
            #pragma unroll
            for (int nf = 0; nf < 2; ++nf) {
                acc[mf][nf + 2] = MFMA16(a0[mf][0], b1[nf][0], acc[mf][nf + 2]);
                acc[mf][nf + 2] = MFMA16(a0[mf][1], b1[nf][1], acc[mf][nf + 2]);
            }
        __builtin_amdgcn_s_setprio(0);
        __builtin_amdgcn_s_barrier();

        // ph3: stage t+2.A.h0 -> cur, MFMA (M1,N0)
        if (s2) stA(t + 2, 0, cur);
        __builtin_amdgcn_s_barrier();
        __builtin_amdgcn_s_setprio(1);
        #pragma unroll
        for (int mf = 0; mf < 4; ++mf)
            #pragma unroll
            for (int nf = 0; nf < 2; ++nf) {
                acc[mf + 4][nf] = MFMA16(a1[mf][0], b0[nf][0], acc[mf + 4][nf]);
                acc[mf + 4][nf] = MFMA16(a1[mf][1], b0[nf][1], acc[mf + 4][nf]);
            }
        __builtin_amdgcn_s_setprio(0);
        __builtin_amdgcn_s_barrier();

        // ph4: stage t+2.A.h1 -> cur, MFMA (M1,N1), counted vmcnt
        if (s2) stA(t + 2, 1, cur);
        __builtin_amdgcn_s_barrier();
        __builtin_amdgcn_s_setprio(1);
        #pragma unroll
        for (int mf = 0; mf < 4; ++mf)
            #pragma unroll
            for (int nf = 0; nf < 2; ++nf) {
                acc[mf + 4][nf + 2] = MFMA16(a1[mf][0], b1[nf][0], acc[mf + 4][nf + 2]);
                acc[mf + 4][nf + 2] = MFMA16(a1[mf][1], b1[nf][1], acc[mf + 4][nf + 2]);
            }
        __builtin_amdgcn_s_setprio(0);
        if (s2)      asm volatile("s_waitcnt vmcnt(4)" ::: "memory");
        else if (s1) asm volatile("s_waitcnt vmcnt(0)" ::: "memory");
        __builtin_amdgcn_s_barrier();
    }

    // ---------------- epilogue ----------------
    const int sel = n0 >> 11;
    if (sel == 2) {
        unsigned short* VtO = (unsigned short*)O2;
        #pragma unroll
        for (int mf = 0; mf < 8; ++mf)
            #pragma unroll
            for (int nf = 0; nf < 4; ++nf) {
                int n = (n0 & 2047) + wc * 64 + nf * 16 + col;
                int hh = n >> 7, dv = n & 127;
                ushort4 pk;
                pk.x = f2b(acc[mf][nf][0]); pk.y = f2b(acc[mf][nf][1]);
                pk.z = f2b(acc[mf][nf][2]); pk.w = f2b(acc[mf][nf][3]);
                *(ushort4*)&VtO[(size_t)hh * (HD * S) + (size_t)dv * S +
                                m0 + wr * 128 + mf * 16 + quad * 4] = pk;
            }
    } else {
        unsigned short* C = (unsigned short*)(sel == 0 ? O0 : O1);
        const float* wgt = (sel == 0) ? qw : kw;
        const float extra = (sel == 0)
            ? 0.08838834764831845f * 1.4426950408889634f : 1.0f;
        float wv4[4];
        #pragma unroll
        for (int nf = 0; nf < 4; ++nf)
            wv4[nf] = wgt[(wc & 1) * 64 + nf * 16 + col];
        #pragma unroll
        for (int mf = 0; mf < 8; ++mf)
            #pragma unroll
            for (int r = 0; r < 4; ++r) {
                float ss = 0.0f;
                #pragma unroll
                for (int nf = 0; nf < 4; ++nf) ss += acc[mf][nf][r] * acc[mf][nf][r];
                #pragma unroll
                for (int d = 1; d < 16; d <<= 1) ss += __shfl_xor(ss, d, 64);
                if (col == 0) red[wc][wr * 128 + mf * 16 + quad * 4 + r] = ss;
            }
        __syncthreads();
        #pragma unroll
        for (int mf = 0; mf < 8; ++mf) {
            float rsc[4];
            #pragma unroll
            for (int r = 0; r < 4; ++r) {
                int idx = wr * 128 + mf * 16 + quad * 4 + r;
                float tot = red[wc & 6][idx] + red[(wc & 6) + 1][idx];
                rsc[r] = rsqrtf(tot * (1.0f / HD) + 1e-6f) * extra;
            }
            #pragma unroll
            for (int nf = 0; nf < 4; ++nf)
                #pragma unroll
                for (int r = 0; r < 4; ++r)
                    C[(size_t)(m0 + wr * 128 + mf * 16 + quad * 4 + r) * 2048 +
                      (n0 & 2047) + wc * 64 + nf * 16 + col] =
                        f2b(acc[mf][nf][r] * rsc[r] * wv4[nf]);
        }
    }
}

// ---------------- bf16 NT GEMM 128x128 (round-2 proven), fp32 out --------
// Full-fill grid for the out-projection: 512 blocks on 256 CUs.
__global__ __launch_bounds__(256) void gemm_out(
    const unsigned short* __restrict__ A, const unsigned short* __restrict__ B,
    float* __restrict__ C)
{
    __shared__ short As[128 * 32];
    __shared__ short Bs[128 * 32];

    const int tid = threadIdx.x;
    const int m0 = blockIdx.y * 128, n0 = blockIdx.x * 128;
    const int w = tid >> 6, lane = tid & 63, col = lane & 15, quad = lane >> 4;
    const int mw = (w >> 1) * 64, nw = (w & 1) * 64;

    const int r0 = tid >> 2, k80 = (tid & 3) << 3;
    const size_t aoff = (size_t)(m0 + r0) * 2048 + k80;
    const size_t boff = (size_t)(n0 + r0) * 2048 + k80;

    f32x4 acc[4][4];
    #pragma unroll
    for (int i = 0; i < 4; ++i)
        #pragma unroll
        for (int j = 0; j < 4; ++j)
            #pragma unroll
            for (int r = 0; r < 4; ++r) acc[i][j][r] = 0.0f;

    for (int k0 = 0; k0 < 2048; k0 += 32) {
        gld16(&A[aoff + k0],               &As[tid * 8]);
        gld16(&A[aoff + 64 * 2048 + k0],   &As[(tid + 256) * 8]);
        gld16(&B[boff + k0],               &Bs[tid * 8]);
        gld16(&B[boff + 64 * 2048 + k0],   &Bs[(tid + 256) * 8]);
        __syncthreads();
        bf16x8 af[4], bf[4];
        #pragma unroll
        for (int i = 0; i < 4; ++i)
            af[i] = *(const bf16x8*)&As[(mw + 16 * i + col) * 32 + quad * 8];
        #pragma unroll
        for (int j = 0; j < 4; ++j)
            bf[j] = *(const bf16x8*)&Bs[(nw + 16 * j + col) * 32 + quad * 8];
        #pragma unroll
        for (int i = 0; i < 4; ++i)
            #pragma unroll
            for (int j = 0; j < 4; ++j)
                acc[i][j] = MFMA16(af[i], bf[j], acc[i][j]);
        __syncthreads();
    }

    #pragma unroll
    for (int i = 0; i < 4; ++i)
        #pragma unroll
        for (int j = 0; j < 4; ++j)
            #pragma unroll
            for (int r = 0; r < 4; ++r)
                C[(size_t)(m0 + mw + 16 * i + quad * 4 + r) * 2048 + n0 + nw + 16 * j + col] = acc[i][j][r];
}

// ---------------- MFMA flash attention v5 (round-3 proven) ---------------
// BQ=128 (32 q-rows/wave), BK=64, double-buffered K/V via global_load_lds.
// exp2 with pre-folded log2e Q-scale; l via MFMA against all-ones B; all
// LDS fragment addresses base+imm; staging pointers advance by const.
struct FlashSmem {
    short Ks[2][8192];   // [buf][ds][key][chunk]
    short Vs[2][8192];   // [buf][ks][dv][chunk]
    short Ps[8192];      // [128 rows][64], XOR-swizzled
};

__global__ __launch_bounds__(256, 2) void flash_mfma(
    const unsigned short* __restrict__ Qg, const unsigned short* __restrict__ Kg,
    const unsigned short* __restrict__ Vt, unsigned short* __restrict__ Ctx)
{
    __shared__ FlashSmem sm;

    const int tid = threadIdx.x;
    const int w = tid >> 6, lane = tid & 63, col = lane & 15, quad = lane >> 4;
    const int q0 = blockIdx.x * 128, h = blockIdx.y;

    bf16x8 aq[2][4];
    #pragma unroll
    for (int qs = 0; qs < 2; ++qs) {
        const size_t qoff = (size_t)(q0 + w * 32 + qs * 16 + col) * 2048 + h * 128 + quad * 8;
        #pragma unroll
        for (int ds = 0; ds < 4; ++ds)
            aq[qs][ds] = *(const bf16x8*)&Qg[qoff + ds * 32];
    }

    const unsigned short* kga[4];
    const unsigned short* vga[4];
    #pragma unroll
    for (int it = 0; it < 4; ++it) {
        int c = tid + (it << 8);
        {   int ds = c >> 8, rem = c & 255, key = rem >> 2, ch = rem & 3;
            int g = ch ^ ((key >> 1) & 3);
            kga[it] = &Kg[(size_t)key * 2048 + h * 128 + ds * 32 + g * 8]; }
        {   int ks = c >> 9, rem = c & 511, dv = rem >> 2, ch = rem & 3;
            int g = ch ^ ((dv >> 1) & 3);
            vga[it] = &Vt[(size_t)h * (HD * S) + (size_t)dv * S + ks * 32 + g * 8]; }
    }

    const int fb = col * 32 + ((quad ^ ((col >> 1) & 3)) << 3);
    int ap_off[2][2];
    #pragma unroll
    for (int qs = 0; qs < 2; ++qs) {
        int qrow = w * 32 + qs * 16 + col;
        #pragma unroll
        for (int ks = 0; ks < 2; ++ks) {
            int k0 = ks * 32 + quad * 8;
            ap_off[ks][qs] = qrow * 64 + (k0 ^ ((qrow & 7) << 3));
        }
    }
    int psb2[2][4];
    #pragma unroll
    for (int qs = 0; qs < 2; ++qs)
        #pragma unroll
        for (int r = 0; r < 4; ++r) {
            int ql = w * 32 + qs * 16 + quad * 4 + r;
            int s = (ql & 7) << 3;
            psb2[qs][r] = ql * 64 + (col ^ (s & 8)) + (s & 48);
        }

    bf16x8 vone;
    #pragma unroll
    for (int i = 0; i < 8; ++i) vone[i] = (short)0x3F80;

    f32x4 lacc[2];
    f32x4 o[2][8];
    #pragma unroll
    for (int qs = 0; qs < 2; ++qs) {
        #pragma unroll
        for (int r = 0; r < 4; ++r) lacc[qs][r] = 0.0f;
        #pragma unroll
        for (int nj = 0; nj < 8; ++nj)
            #pragma unroll
            for (int r = 0; r < 4; ++r) o[qs][nj][r] = 0.0f;
    }

    auto stage = [&](int b) {
        #pragma unroll
        for (int it = 0; it < 4; ++it) {
            gld16(kga[it], &sm.Ks[b][(tid + (it << 8)) * 8]);
            kga[it] += 64 * 2048;
        }
        #pragma unroll
        for (int it = 0; it < 4; ++it) {
            gld16(vga[it], &sm.Vs[b][(tid + (it << 8)) * 8]);
            vga[it] += 64;
        }
    };

    auto compute = [&](int b) {
        f32x4 sc[2][4];
        #pragma unroll
        for (int qs = 0; qs < 2; ++qs)
            #pragma unroll
            for (int kj = 0; kj < 4; ++kj)
                #pragma unroll
                for (int r = 0; r < 4; ++r) sc[qs][kj][r] = 0.0f;
        __builtin_amdgcn_s_setprio(1);
        #pragma unroll
        for (int ds = 0; ds < 4; ++ds)
            #pragma unroll
            for (int kj = 0; kj < 4; ++kj) {
                bf16x8 bk = *(const bf16x8*)&sm.Ks[b][fb + ds * 2048 + kj * 512];
                sc[0][kj] = MFMA16(aq[0][ds], bk, sc[0][kj]);
                sc[1][kj] = MFMA16(aq[1][ds], bk, sc[1][kj]);
            }
        __builtin_amdgcn_s_setprio(0);

        #pragma unroll
        for (int qs = 0; qs < 2; ++qs)
            #pragma unroll
            for (int kj = 0; kj < 4; ++kj)
                #pragma unroll
                for (int r = 0; r < 4; ++r)
                    sm.Ps[psb2[qs][r] ^ (kj * 16)] = (short)f2b(fexp2(sc[qs][kj][r]));

        __builtin_amdgcn_s_setprio(1);
        #pragma unroll
        for (int ks = 0; ks < 2; ++ks) {
            bf16x8 ap0 = *(const bf16x8*)&sm.Ps[ap_off[ks][0]];
            bf16x8 ap1 = *(const bf16x8*)&sm.Ps[ap_off[ks][1]];
            lacc[0] = MFMA16(ap0, vone, lacc[0]);
            lacc[1] = MFMA16(ap1, vone, lacc[1]);
            #pragma unroll
            for (int nj = 0; nj < 8; ++nj) {
                bf16x8 bv = *(const bf16x8*)&sm.Vs[b][fb + ks * 4096 + nj * 512];
                o[0][nj] = MFMA16(ap0, bv, o[0][nj]);
                o[1][nj] = MFMA16(ap1, bv, o[1][nj]);
            }
        }
        __builtin_amdgcn_s_setprio(0);
    };

    stage(0);
    for (int j0 = 0; j0 < S; j0 += 128) {
        __syncthreads();
        stage(1);
        compute(0);
        __syncthreads();
        if (j0 + 128 < S) stage(0);
        compute(1);
    }

    #pragma unroll
    for (int qs = 0; qs < 2; ++qs) {
        float inv[4];
        #pragma unroll
        for (int r = 0; r < 4; ++r) inv[r] = 1.0f / lacc[qs][r];
        #pragma unroll
        for (int nj = 0; nj < 8; ++nj)
            #pragma unroll
            for (int r = 0; r < 4; ++r)
                Ctx[(size_t)(q0 + w * 32 + qs * 16 + quad * 4 + r) * 2048 + h * 128 + nj * 16 + col] =
                    f2b(o[qs][nj][r] * inv[r]);
    }
}

extern "C" void kernel_launch(void* const* d_in, const int* in_sizes, int n_in,
                              void* d_out, int out_size, void* d_ws, size_t ws_size,
                              hipStream_t stream)
{
    const float* x  = (const float*)d_in[0];
    const float* wq = (const float*)d_in[1];
    const float* wk = (const float*)d_in[2];
    const float* wv = (const float*)d_in[3];
    const float* wo = (const float*)d_in[4];
    const float* qw = (const float*)d_in[5];
    const float* kw = (const float*)d_in[6];
    float* out = (float*)d_out;

    const size_t MB = 1u << 20;
    char* ws = (char*)d_ws;
    unsigned short* xb    = (unsigned short*)(ws);             // 16 MB; later Ctx
    unsigned short* Wqkvb = (unsigned short*)(ws + 16 * MB);   // 24 MB
    unsigned short* Wob   = (unsigned short*)(ws + 40 * MB);   //  8 MB
    unsigned short* Qb    = (unsigned short*)(ws + 48 * MB);   // 16 MB
    unsigned short* Kb    = (unsigned short*)(ws + 64 * MB);   // 16 MB
    unsigned short* Vt    = (unsigned short*)(ws + 80 * MB);   // 16 MB [h][dv][s]
    unsigned short* Ctx   = xb;                                // overlay after proj

    cvt_all<<<dim3(8192, 5), dim3(256), 0, stream>>>(x, wq, wk, wv, wo, xb, Wqkvb, Wob);

    // fused QKV projection + RMSNorm epilogue + transposed V write
    gemm8_qkv<<<dim3(24, 16), dim3(512), 0, stream>>>(xb, Wqkvb, Qb, Kb, Vt, qw, kw);

    flash_mfma<<<dim3(32, 16), dim3(256), 0, stream>>>(Qb, Kb, Vt, Ctx);

    // out-projection: 128^2 tile, full-fill 512-block grid
    gemm_out<<<dim3(16, 32), dim3(256), 0, stream>>>(Ctx, Wob, out);
}